// Round 9
// baseline (68.662 us; speedup 1.0000x reference)
//
#include <hip/hip_runtime.h>
#include <hip/hip_bf16.h>

// Renderer interpolation: out[p, d] = sum_k bary[p,k] * attributes[faces[wrap(pix[p])][k], d]
// mask[p] = (pix[p] != -1).  H=W=1024, D=32, F=100000, V=50000.
//
// Round-9: FACE-MAJOR bf16 gather table to cut line-touches per pixel 3 -> 2.
// Evidence: r1=3 touches/pix=65us, r4=6 half-line=106us, r5=12 quarter-line=140us;
// residency (r5/r6/r7), ILP (r3), L1-bypass (r8) all non-levers -> cost ~ touches.
// Prep builds table[f] (256B record, 25.6MB in ws):
//   line0 (128B): lane t's 16B = [v0 dims 4t..4t+3 | v1 dims 4t..4t+3] as bf16
//   line1 (64B+64B pad): v2 row plain bf16 (lane t reads 8B at t*8); pad unread.
// Main = r1 structure minus faces stage: per pixel TWO gather instructions
// (dwordx4 line0 + dwordx2 line1) = 2 requests / 2 line-touches, zero shuffles.
// bf16 RTNE numerics: r6/r7 passed at absmax 0.0156 (threshold 8.56e-2).

typedef float fvec4 __attribute__((ext_vector_type(4)));
typedef unsigned short usvec8 __attribute__((ext_vector_type(8)));
typedef unsigned short usvec4 __attribute__((ext_vector_type(4)));

__device__ __forceinline__ float bf16_to_f32(unsigned short h) {
    unsigned int u = ((unsigned int)h) << 16;
    return __builtin_bit_cast(float, u);
}

__device__ __forceinline__ unsigned short f32_to_bf16(float x) {
    unsigned int u = __builtin_bit_cast(unsigned int, x);
    unsigned int r = (u + 0x7FFFu + ((u >> 16) & 1u)) >> 16;   // RTNE
    return (unsigned short)r;
}

// ---- prep: build face-major table. 8 lanes per face. ----
__global__ __launch_bounds__(256) void Renderer_facetab_kernel(
    const int* __restrict__ faces,      // (F,3)
    const float* __restrict__ attr,     // (V,32)
    unsigned short* __restrict__ table, // (F,128) bf16 slots (256B/face)
    int F)
{
    int tid = blockIdx.x * blockDim.x + threadIdx.x;
    if (tid >= F * 8) return;
    int f = tid >> 3;
    int t = tid & 7;

    int v0 = faces[3 * f + 0];
    int v1 = faces[3 * f + 1];
    int v2 = faces[3 * f + 2];

    const fvec4* A = reinterpret_cast<const fvec4*>(attr);
    fvec4 c0 = A[v0 * 8 + t];   // v0 dims 4t..4t+3
    fvec4 c1 = A[v1 * 8 + t];
    fvec4 c2 = A[v2 * 8 + t];

    usvec8 rec;
    rec[0] = f32_to_bf16(c0[0]); rec[1] = f32_to_bf16(c0[1]);
    rec[2] = f32_to_bf16(c0[2]); rec[3] = f32_to_bf16(c0[3]);
    rec[4] = f32_to_bf16(c1[0]); rec[5] = f32_to_bf16(c1[1]);
    rec[6] = f32_to_bf16(c1[2]); rec[7] = f32_to_bf16(c1[3]);
    // line0: byte offset f*256 + t*16
    reinterpret_cast<usvec8*>(table)[f * 16 + t] = rec;

    usvec4 r2;
    r2[0] = f32_to_bf16(c2[0]); r2[1] = f32_to_bf16(c2[1]);
    r2[2] = f32_to_bf16(c2[2]); r2[3] = f32_to_bf16(c2[3]);
    // line1: byte offset f*256 + 128 + t*8 (ushort index f*128 + 64 + t*4)
    *reinterpret_cast<usvec4*>(table + (size_t)f * 128 + 64 + t * 4) = r2;
    // bytes f*256+192..256 are pad: never read, left uninitialized
}

// ---- main: r1 structure, 2 gathers/pixel from the face-major table ----
__global__ __launch_bounds__(256) void Renderer_interp_face_kernel(
    const int* __restrict__ pix,              // (npix)
    const float* __restrict__ bary,           // (npix,3)
    const unsigned short* __restrict__ table, // (F,128) bf16
    float* __restrict__ out,                  // (npix,32)
    float* __restrict__ mask,                 // (npix)
    int npix, int F)
{
    int tid = blockIdx.x * blockDim.x + threadIdx.x;
    int p = tid >> 3;      // pixel
    int t = tid & 7;       // d-chunk: dims 4t..4t+3
    if (p >= npix) return;

    int fraw = pix[p];
    int f = (fraw < 0) ? (fraw + F) : fraw;   // mode='wrap': -1 -> F-1

    float w0 = bary[3 * p + 0];
    float w1 = bary[3 * p + 1];
    float w2 = bary[3 * p + 2];

    // gather 1: 128B line0 -> lane t: v0/v1 chunks (16B)
    usvec8 r01 = reinterpret_cast<const usvec8*>(table)[f * 16 + t];
    // gather 2: 64B of line1 -> lane t: v2 chunk (8B)
    usvec4 r2 = *reinterpret_cast<const usvec4*>(
        table + (size_t)f * 128 + 64 + t * 4);

    fvec4 o;
    #pragma unroll
    for (int j = 0; j < 4; ++j) {
        o[j] = w0 * bf16_to_f32(r01[j])
             + w1 * bf16_to_f32(r01[j + 4])
             + w2 * bf16_to_f32(r2[j]);
    }

    reinterpret_cast<fvec4*>(out)[(size_t)p * 8 + t] = o;

    if (t == 0) {
        mask[p] = (fraw != -1) ? 1.0f : 0.0f;
    }
}

// ---- fallback (round-1 structure) if ws too small ----
__global__ __launch_bounds__(256) void Renderer_interp_kernel(
    const int* __restrict__ pix, const float* __restrict__ bary,
    const int* __restrict__ faces, const float* __restrict__ attr,
    float* __restrict__ out, float* __restrict__ mask, int npix, int F)
{
    int tid = blockIdx.x * blockDim.x + threadIdx.x;
    int p = tid >> 3;
    int t = tid & 7;
    if (p >= npix) return;
    int fraw = pix[p];
    int f = (fraw < 0) ? (fraw + F) : fraw;
    int base = 3 * f;
    int v0 = faces[base + 0], v1 = faces[base + 1], v2 = faces[base + 2];
    float w0 = bary[3 * p + 0], w1 = bary[3 * p + 1], w2 = bary[3 * p + 2];
    const fvec4* A = reinterpret_cast<const fvec4*>(attr);
    fvec4 r0 = A[v0 * 8 + t], r1 = A[v1 * 8 + t], r2 = A[v2 * 8 + t];
    fvec4 o = w0 * r0 + w1 * r1 + w2 * r2;
    reinterpret_cast<fvec4*>(out)[(size_t)p * 8 + t] = o;
    if (t == 0) mask[p] = (fraw != -1) ? 1.0f : 0.0f;
}

extern "C" void kernel_launch(void* const* d_in, const int* in_sizes, int n_in,
                              void* d_out, int out_size, void* d_ws, size_t ws_size,
                              hipStream_t stream) {
    const int*   pix   = (const int*)d_in[0];
    const float* bary  = (const float*)d_in[1];
    const int*   faces = (const int*)d_in[2];
    const float* attr  = (const float*)d_in[3];

    int npix = in_sizes[0];        // 1048576
    int F    = in_sizes[2] / 3;    // 100000

    float* out  = (float*)d_out;                      // (npix,32)
    float* mask = (float*)d_out + (size_t)npix * 32;  // (npix,)

    size_t need = (size_t)F * 256;                    // 25.6MB face-major table

    if (ws_size >= need) {
        unsigned short* table = (unsigned short*)d_ws;
        int nprep = F * 8;
        Renderer_facetab_kernel<<<(nprep + 255) / 256, 256, 0, stream>>>(
            faces, attr, table, F);
        int total = npix * 8;
        Renderer_interp_face_kernel<<<(total + 255) / 256, 256, 0, stream>>>(
            pix, bary, table, out, mask, npix, F);
    } else {
        int total = npix * 8;
        Renderer_interp_kernel<<<(total + 255) / 256, 256, 0, stream>>>(
            pix, bary, faces, attr, out, mask, npix, F);
    }
}